// Round 3
// baseline (233.401 us; speedup 1.0000x reference)
//
#include <hip/hip_runtime.h>
#include <cstdint>

#pragma clang fp contract(off)

#define R_N       2000
#define NPAD      2048
#define NCLS      20

__device__ __forceinline__ unsigned int umin2(unsigned int a, unsigned int b) {
  return a < b ? a : b;
}

// Robust scalar-dim read: int32/int64 (LE) or float32/float64 materialization.
__device__ __forceinline__ double read_dim(const void* p) {
  int iv = *(const int*)p;
  if (iv >= 1 && iv <= 1000000) return (double)iv;
  float fv = *(const float*)p;
  if (fv >= 1.0f && fv <= 1000000.0f) return (double)fv;
  return *(const double*)p;
}

__global__ __launch_bounds__(256) void det_kernel(
    const float* __restrict__ rois,   // (2000,4)  y1,x1,y2,x2
    const float* __restrict__ loc,    // (2000,84) = (2000,21,4)
    const float* __restrict__ score,  // (2000,21)
    const void* __restrict__ hptr,
    const void* __restrict__ wptr,
    float* __restrict__ out)          // 280000 f32: out(20,2000,5) | labels(20,2000) | keep(20,2000)
{
  __shared__ double sbd[R_N][4];       // decoded boxes, f64, original order (64000 B)
  __shared__ ulonglong2 keys[NPAD];    // .x = f64 prob bits (0 if invalid), .y = ~r  (32768 B)
  __shared__ unsigned int red[4];

  const int c = blockIdx.x;            // fg class c -> score/loc column c+1
  const int t = threadIdx.x;
  const double H = read_dim(hptr);
  const double W = read_dim(wptr);

  // ---- phase 1: f64 softmax prob + f64 box decode ----
  for (int r = t; r < NPAD; r += 256) {
    if (r < R_N) {
      const float* sc = score + r * 21;
      double m = (double)sc[0];
      #pragma unroll
      for (int k = 1; k < 21; ++k) m = fmax(m, (double)sc[k]);
      double sum = 0.0;
      #pragma unroll
      for (int k = 0; k < 21; ++k) sum += exp((double)sc[k] - m);
      double p = exp((double)sc[c + 1] - m) / sum;

      double b0 = (double)rois[r*4+0], b1 = (double)rois[r*4+1];
      double b2 = (double)rois[r*4+2], b3 = (double)rois[r*4+3];
      double sh  = b2 - b0,        sw  = b3 - b1;
      double scy = b0 + 0.5 * sh,  scx = b1 + 0.5 * sw;
      const float* l4 = loc + r * 84 + (c + 1) * 4;
      double dy = (double)l4[0], dx = (double)l4[1];
      double dh = (double)l4[2], dw = (double)l4[3];
      double cy = dy * sh + scy;
      double cx = dx * sw + scx;
      double hh = exp(dh) * sh;
      double ww = exp(dw) * sw;
      double y1 = fmin(fmax(cy - 0.5 * hh, 0.0), H);
      double x1 = fmin(fmax(cx - 0.5 * ww, 0.0), W);
      double y2 = fmin(fmax(cy + 0.5 * hh, 0.0), H);
      double x2 = fmin(fmax(cx + 0.5 * ww, 0.0), W);
      sbd[r][0] = y1; sbd[r][1] = x1; sbd[r][2] = y2; sbd[r][3] = x2;

      unsigned long long pb =
          (p > 0.05) ? (unsigned long long)__double_as_longlong(p) : 0ull;
      keys[r] = make_ulonglong2(pb, (unsigned long long)(unsigned int)(~r));
    } else {
      keys[r] = make_ulonglong2(0ull, (unsigned long long)(unsigned int)(~r));
    }
  }
  __syncthreads();

  // ---- phase 2: bitonic sort, descending on (prob bits, ~r) => prob desc, idx asc ----
  for (int k = 2; k <= NPAD; k <<= 1) {
    for (int js = k >> 1; js > 0; js >>= 1) {
      #pragma unroll
      for (int p4 = 0; p4 < 4; ++p4) {
        int p = t + 256 * p4;
        int i = ((p & ~(js - 1)) << 1) | (p & (js - 1));
        int j = i | js;
        ulonglong2 a = keys[i], b = keys[j];
        bool altb = (a.x < b.x) || (a.x == b.x && a.y < b.y);
        bool ddir = ((i & k) == 0);          // true -> descending run
        if (altb == ddir) { keys[i] = b; keys[j] = a; }
      }
      __syncthreads();
    }
  }

  // ---- phase 3: load my 8 sorted slots into registers (f64) ----
  double bx[8][4];
  double ar[8];
  bool   alive[8];
  #pragma unroll
  for (int q = 0; q < 8; ++q) {
    int j = t + 256 * q;
    ulonglong2 kk = keys[j];
    int idx = (int)(~(unsigned int)kk.y);
    alive[q] = (kk.x != 0ull);
    if (idx < R_N) {
      bx[q][0] = sbd[idx][0]; bx[q][1] = sbd[idx][1];
      bx[q][2] = sbd[idx][2]; bx[q][3] = sbd[idx][3];
    } else {
      bx[q][0] = bx[q][1] = bx[q][2] = bx[q][3] = 0.0;
    }
    ar[q] = (bx[q][2] - bx[q][0]) * (bx[q][3] - bx[q][1]);
  }

  // ---- phase 4: greedy NMS, find-next-min (iterations == #kept) ----
  const unsigned int INFU = 0x7fffffffu;
  const int lane = t & 63, wv = t >> 6;
  while (true) {
    unsigned int local = INFU;
    #pragma unroll
    for (int q = 0; q < 8; ++q)
      if (alive[q]) local = umin2(local, (unsigned int)(t + 256 * q));
    #pragma unroll
    for (int off = 32; off; off >>= 1)
      local = umin2(local, (unsigned int)__shfl_xor((int)local, off));
    __syncthreads();                       // protect red[] from prior-iter reads
    if (lane == 0) red[wv] = local;
    __syncthreads();
    unsigned int cur = umin2(umin2(red[0], red[1]), umin2(red[2], red[3]));
    if (cur == INFU) break;

    // broadcast kept box (uniform LDS reads)
    ulonglong2 kc = keys[cur];
    int cidx = (int)(~(unsigned int)kc.y);
    double iy1 = sbd[cidx][0], ix1 = sbd[cidx][1];
    double iy2 = sbd[cidx][2], ix2 = sbd[cidx][3];
    double iar = (iy2 - iy1) * (ix2 - ix1);

    // owner thread scatters the output row
    if ((int)(cur & 255u) == t) {
      int row = c * R_N + (int)cur;
      double pk = __longlong_as_double((long long)kc.x);
      out[row * 5 + 0] = (float)iy1;
      out[row * 5 + 1] = (float)ix1;
      out[row * 5 + 2] = (float)iy2;
      out[row * 5 + 3] = (float)ix2;
      out[row * 5 + 4] = (float)pk;
      out[200000 + row] = (float)(c + 1);   // labels
      out[240000 + row] = 1.0f;             // keep
    }

    // suppress: exact reference op order  inter/(max(a_i+a_j-inter,1e-9)) > 0.3
    #pragma unroll
    for (int q = 0; q < 8; ++q) {
      int j = t + 256 * q;
      if (alive[q]) {
        if (j == (int)cur) {
          alive[q] = false;
        } else if (j > (int)cur) {
          double ty  = fmax(iy1, bx[q][0]);
          double tx  = fmax(ix1, bx[q][1]);
          double by  = fmin(iy2, bx[q][2]);
          double bxx = fmin(ix2, bx[q][3]);
          double wh0 = fmax(by - ty, 0.0);
          double wh1 = fmax(bxx - tx, 0.0);
          double inter = wh0 * wh1;
          double uni = iar + ar[q] - inter;
          double iou = inter / fmax(uni, 1e-9);
          if (iou > 0.3) alive[q] = false;
        }
      }
    }
  }
}

extern "C" void kernel_launch(void* const* d_in, const int* in_sizes, int n_in,
                              void* d_out, int out_size, void* d_ws, size_t ws_size,
                              hipStream_t stream) {
  const float* rois  = (const float*)d_in[0];
  const float* loc   = (const float*)d_in[1];
  const float* score = (const float*)d_in[2];
  const void*  hp    = d_in[3];
  const void*  wp    = d_in[4];
  float* out = (float*)d_out;

  // all non-kept rows are exactly zero -> zero the whole output, scatter kept rows
  hipMemsetAsync(d_out, 0, (size_t)out_size * sizeof(float), stream);
  det_kernel<<<dim3(NCLS), dim3(256), 0, stream>>>(rois, loc, score, hp, wp, out);
}

// Round 4
// 150.555 us; speedup vs baseline: 1.5503x; 1.5503x over previous
//
#include <hip/hip_runtime.h>
#include <cstdint>

#pragma clang fp contract(off)

#define R_N   2000
#define C1    21
#define NCLS  20
#define OUT_LBL   200000
#define OUT_KEEP  240000

__device__ __forceinline__ double read_dim(const void* p) {
  int iv = *(const int*)p;
  if (iv >= 1 && iv <= 1000000) return (double)iv;
  float fv = *(const float*)p;
  if (fv >= 1.0f && fv <= 1000000.0f) return (double)fv;
  return *(const double*)p;
}

// ---- kernel 1: f64 exp tables (softmax exps+sums, exp(dh)/exp(dw)) ----
__global__ __launch_bounds__(256) void prep_kernel(
    const float* __restrict__ score, const float* __restrict__ loc,
    double* __restrict__ exps, double* __restrict__ sums, double* __restrict__ ehw)
{
  int gid = blockIdx.x * 256 + threadIdx.x;
  int r = gid >> 2, sub = gid & 3;
  if (r >= R_N) return;
  if (sub == 0) {
    const float* sc = score + r * C1;
    double m = (double)sc[0];
    #pragma unroll
    for (int k = 1; k < C1; ++k) m = fmax(m, (double)sc[k]);
    double s = 0.0;
    #pragma unroll
    for (int k = 0; k < C1; ++k) { double e = exp((double)sc[k] - m); exps[r*C1+k] = e; s += e; }
    sums[r] = s;
  } else {
    int k0 = (sub - 1) * 7;
    for (int k = k0; k < k0 + 7; ++k) {
      ehw[(r*C1+k)*2+0] = exp((double)loc[r*84 + k*4 + 2]);
      ehw[(r*C1+k)*2+1] = exp((double)loc[r*84 + k*4 + 3]);
    }
  }
}

// ---- kernel 2: per-class decode + compact + sort + chunked NMS ----
__global__ __launch_bounds__(256) void det_kernel(
    const float* __restrict__ rois, const float* __restrict__ loc,
    const float* __restrict__ score,
    const void* __restrict__ hptr, const void* __restrict__ wptr,
    float* __restrict__ out,
    const double* __restrict__ exps, const double* __restrict__ sums,
    const double* __restrict__ ehw, int use_ws)
{
  __shared__ double sbd[R_N][4];        // decoded boxes by original index (64000 B)
  __shared__ ulonglong2 keys[2048];     // (.x = f64 prob bits, .y = ~r)   (32768 B)
  __shared__ double klist[2][64][5];    // kept boxes of current chunk     (5120 B)
  __shared__ int kcnt[2];
  __shared__ int wsum[4];

  const int cls = blockIdx.x;           // fg class -> column cls+1
  const int t = threadIdx.x;
  const int lane = t & 63, wid = t >> 6;
  const double H = read_dim(hptr), W = read_dim(wptr);

  // ---- decode 8 consecutive rows per thread ----
  ulonglong2 rk[8];
  int vmask = 0;
  #pragma unroll
  for (int u = 0; u < 8; ++u) {
    int r = 8 * t + u;
    rk[u] = make_ulonglong2(0ull, 0ull);
    if (r < R_N) {
      const float* l4 = loc + r*84 + (cls+1)*4;
      double p, eh, ew;
      if (use_ws) {
        p  = exps[r*C1 + cls + 1] / sums[r];
        eh = ehw[(r*C1 + cls + 1)*2 + 0];
        ew = ehw[(r*C1 + cls + 1)*2 + 1];
      } else {
        const float* sc = score + r * C1;
        double m = (double)sc[0];
        #pragma unroll
        for (int k = 1; k < C1; ++k) m = fmax(m, (double)sc[k]);
        double s = 0.0;
        #pragma unroll
        for (int k = 0; k < C1; ++k) s += exp((double)sc[k] - m);
        p  = exp((double)sc[cls+1] - m) / s;
        eh = exp((double)l4[2]);
        ew = exp((double)l4[3]);
      }
      double b0 = (double)rois[r*4+0], b1 = (double)rois[r*4+1];
      double b2 = (double)rois[r*4+2], b3 = (double)rois[r*4+3];
      double sh  = b2 - b0,       sw  = b3 - b1;
      double scy = b0 + 0.5*sh,   scx = b1 + 0.5*sw;
      double dy = (double)l4[0],  dx = (double)l4[1];
      double cy = dy*sh + scy,    cx = dx*sw + scx;
      double hh = eh*sh,          ww = ew*sw;
      double y1 = fmin(fmax(cy - 0.5*hh, 0.0), H);
      double x1 = fmin(fmax(cx - 0.5*ww, 0.0), W);
      double y2 = fmin(fmax(cy + 0.5*hh, 0.0), H);
      double x2 = fmin(fmax(cx + 0.5*ww, 0.0), W);
      sbd[r][0]=y1; sbd[r][1]=x1; sbd[r][2]=y2; sbd[r][3]=x2;
      bool val = p > 0.05;
      unsigned long long pb = val ? (unsigned long long)__double_as_longlong(p) : 0ull;
      rk[u] = make_ulonglong2(pb, (unsigned long long)(unsigned int)(~r));
      vmask |= (val ? 1 : 0) << u;
    }
  }

  // ---- stable compaction of valid entries (block scan) ----
  int cnt = __popc(vmask);
  int x = cnt;
  #pragma unroll
  for (int off = 1; off < 64; off <<= 1) {
    int y = __shfl_up(x, off);
    if (lane >= off) x += y;
  }
  if (lane == 63) wsum[wid] = x;
  __syncthreads();
  int woff = 0;
  #pragma unroll
  for (int w2 = 0; w2 < 4; ++w2) { int s = wsum[w2]; if (w2 < wid) woff += s; }
  const int V = wsum[0] + wsum[1] + wsum[2] + wsum[3];
  int pos = woff + x - cnt;           // exclusive prefix
  #pragma unroll
  for (int u = 0; u < 8; ++u)
    if ((vmask >> u) & 1) keys[pos++] = rk[u];

  int NSORT = 64; while (NSORT < V) NSORT <<= 1;
  for (int j = V + t; j < NSORT; j += 256)
    keys[j] = make_ulonglong2(0ull, (unsigned long long)(unsigned int)(~(unsigned)j));
  __syncthreads();

  // ---- bitonic sort NSORT keys, descending (prob desc, idx asc) ----
  for (int k = 2; k <= NSORT; k <<= 1) {
    for (int js = k >> 1; js > 0; js >>= 1) {
      for (int p = t; p < (NSORT >> 1); p += 256) {
        int i = ((p & ~(js - 1)) << 1) | (p & (js - 1));
        int j = i | js;
        ulonglong2 a = keys[i], b = keys[j];
        bool altb = (a.x < b.x) || (a.x == b.x && a.y < b.y);
        if (altb == ((i & k) == 0)) { keys[i] = b; keys[j] = a; }
      }
      __syncthreads();
    }
  }

  // ---- per-thread slot registers (slot j = t + 256q) ----
  double bx0[8], bx1[8], bx2[8], bx3[8], ar[8];
  unsigned am = 0;                      // alive bitmask over q
  #pragma unroll
  for (int q = 0; q < 8; ++q) {
    int j = t + 256 * q;
    bx0[q]=bx1[q]=bx2[q]=bx3[q]=0.0; ar[q]=0.0;
    if (j < V) {
      int idx = (int)(~(unsigned)keys[j].y);
      double a0=sbd[idx][0], a1=sbd[idx][1], a2=sbd[idx][2], a3=sbd[idx][3];
      bx0[q]=a0; bx1[q]=a1; bx2[q]=a2; bx3[q]=a3;
      ar[q] = (a2 - a0) * (a3 - a1);
      am |= 1u << q;
    }
  }

  // ---- chunked greedy NMS: wave (ch&3) resolves chunk ch in-wave ----
  const int nch = (V + 63) >> 6;
  for (int ch = 0; ch < nch; ++ch) {
    const int buf = ch & 1;
    if (wid == (ch & 3)) {
      const int q = ch >> 2;
      const int s = 64 * ch + lane;
      bool a = (am >> q) & 1;
      double my0=0, my1=0, my2=0, my3=0, mar=0;
      if (a) {
        int idx = (int)(~(unsigned)keys[s].y);
        my0=sbd[idx][0]; my1=sbd[idx][1]; my2=sbd[idx][2]; my3=sbd[idx][3];
        mar = (my2 - my0) * (my3 - my1);
      }
      unsigned long long m = __ballot(a);
      unsigned long long kept = 0;
      while (m) {
        int i = __ffsll((unsigned long long)m) - 1;
        m &= ~(1ull << i);
        kept |= 1ull << i;
        double ky0 = __shfl(my0, i), kx0 = __shfl(my1, i);
        double ky1 = __shfl(my2, i), kx1 = __shfl(my3, i);
        double kar = __shfl(mar, i);
        bool kill = false;
        if ((m >> lane) & 1) {          // still alive => lane > i
          double ty  = fmax(ky0, my0), tx  = fmax(kx0, my1);
          double by  = fmin(ky1, my2), bxx = fmin(kx1, my3);
          double wh0 = fmax(by - ty, 0.0), wh1 = fmax(bxx - tx, 0.0);
          double inter = wh0 * wh1;
          double uni = kar + mar - inter;
          double iou = inter / fmax(uni, 1e-9);
          kill = iou > 0.3;
        }
        m &= ~__ballot(kill);
      }
      am &= ~(1u << q);                 // chunk fully resolved
      if ((kept >> lane) & 1) {
        int kpos = (int)__popcll(kept & ((1ull << lane) - 1ull));
        klist[buf][kpos][0]=my0; klist[buf][kpos][1]=my1;
        klist[buf][kpos][2]=my2; klist[buf][kpos][3]=my3; klist[buf][kpos][4]=mar;
        double pv = __longlong_as_double((long long)keys[s].x);
        int row = cls * R_N + s;
        out[row*5+0]=(float)my0; out[row*5+1]=(float)my1;
        out[row*5+2]=(float)my2; out[row*5+3]=(float)my3;
        out[row*5+4]=(float)pv;
        out[OUT_LBL  + row] = (float)(cls + 1);
        out[OUT_KEEP + row] = 1.0f;
      }
      if (lane == 0) kcnt[buf] = (int)__popcll(kept);
    }
    __syncthreads();
    // ---- cross suppression of future slots against this chunk's kept ----
    const int nk = kcnt[buf];
    const int jmin = 64 * (ch + 1);
    for (int n = 0; n < nk; ++n) {
      double ky0 = klist[buf][n][0], kx0 = klist[buf][n][1];
      double ky1 = klist[buf][n][2], kx1 = klist[buf][n][3];
      double kar = klist[buf][n][4];
      #pragma unroll
      for (int q2 = 0; q2 < 8; ++q2) {
        int j2 = t + 256 * q2;
        if (((am >> q2) & 1) && j2 >= jmin) {
          double ty  = fmax(ky0, bx0[q2]), tx  = fmax(kx0, bx1[q2]);
          double by  = fmin(ky1, bx2[q2]), bxx = fmin(kx1, bx3[q2]);
          double wh0 = fmax(by - ty, 0.0), wh1 = fmax(bxx - tx, 0.0);
          double inter = wh0 * wh1;
          double uni = kar + ar[q2] - inter;
          double iou = inter / fmax(uni, 1e-9);
          if (iou > 0.3) am &= ~(1u << q2);
        }
      }
    }
  }
}

extern "C" void kernel_launch(void* const* d_in, const int* in_sizes, int n_in,
                              void* d_out, int out_size, void* d_ws, size_t ws_size,
                              hipStream_t stream) {
  const float* rois  = (const float*)d_in[0];
  const float* loc   = (const float*)d_in[1];
  const float* score = (const float*)d_in[2];
  const void*  hp    = d_in[3];
  const void*  wp    = d_in[4];
  float* out = (float*)d_out;

  const size_t need = (size_t)(R_N*C1 + R_N + R_N*C1*2) * sizeof(double); // 1,024,000 B
  double* exps = (double*)d_ws;
  double* sums = exps + R_N*C1;
  double* ehw  = sums + R_N;
  int use_ws = (ws_size >= need) ? 1 : 0;

  hipMemsetAsync(d_out, 0, (size_t)out_size * sizeof(float), stream);
  if (use_ws) {
    prep_kernel<<<dim3((R_N*4 + 255)/256), dim3(256), 0, stream>>>(score, loc, exps, sums, ehw);
  }
  det_kernel<<<dim3(NCLS), dim3(256), 0, stream>>>(rois, loc, score, hp, wp, out,
                                                   exps, sums, ehw, use_ws);
}

// Round 5
// 113.809 us; speedup vs baseline: 2.0508x; 1.3229x over previous
//
#include <hip/hip_runtime.h>
#include <cstdint>

#pragma clang fp contract(off)

#define R_N   2000
#define C1    21
#define NCLS  20
#define OUT_LBL   200000
#define OUT_KEEP  240000
#define FMARGIN   4.0f      // abs error bound of f32 (inter - 0.3*uni) is ~0.7 px^2; 4.0 = 5x safety

__device__ __forceinline__ double read_dim(const void* p) {
  int iv = *(const int*)p;
  if (iv >= 1 && iv <= 1000000) return (double)iv;
  float fv = *(const float*)p;
  if (fv >= 1.0f && fv <= 1000000.0f) return (double)fv;
  return *(const double*)p;
}

// ---- kernel 1: transposed f64 tables: prob_t[cls*R_N+r], tab4[(cls*R_N+r)*4]={dy,dx,exp(dh),exp(dw)}
__global__ __launch_bounds__(256) void prep_kernel(
    const float* __restrict__ score, const float* __restrict__ loc,
    double* __restrict__ tab4, double* __restrict__ prob_t)
{
  int r = blockIdx.x * 256 + threadIdx.x;
  if (r >= R_N) return;
  const float* sc = score + r * C1;
  double m = (double)sc[0];
  #pragma unroll
  for (int k = 1; k < C1; ++k) m = fmax(m, (double)sc[k]);
  double e[C1]; double s = 0.0;
  #pragma unroll
  for (int k = 0; k < C1; ++k) { e[k] = exp((double)sc[k] - m); s += e[k]; }
  for (int c = 0; c < NCLS; ++c)
    prob_t[c * R_N + r] = e[c + 1] / s;          // coalesced per c
  for (int c = 0; c < NCLS; ++c) {
    const float* l4 = loc + r * 84 + (c + 1) * 4;
    double* o = tab4 + (size_t)(c * R_N + r) * 4; // 32B/lane coalesced per c
    o[0] = (double)l4[0];
    o[1] = (double)l4[1];
    o[2] = exp((double)l4[2]);
    o[3] = exp((double)l4[3]);
  }
}

// ---- kernel 2: per-class decode + compact + sort + chunked NMS (f32 fast path, f64 exact fallback)
__global__ __launch_bounds__(256) void det_kernel(
    const float* __restrict__ rois, const float* __restrict__ loc,
    const float* __restrict__ score,
    const void* __restrict__ hptr, const void* __restrict__ wptr,
    float* __restrict__ out,
    const double* __restrict__ tab4, const double* __restrict__ prob_t,
    int use_ws)
{
  __shared__ double sbd[R_N][4];        // decoded boxes f64, by original index (64000 B)
  __shared__ ulonglong2 keys[2048];     // (.x = f64 prob bits, .y = ~r)        (32768 B)
  __shared__ double klist64[2][64][5];  // kept boxes f64 (fallback)            (5120 B)
  __shared__ float  klist32[2][64][5];  // kept boxes f32 (fast path)           (2560 B)
  __shared__ int kcnt[2];
  __shared__ int wsum[4];

  const int cls = blockIdx.x;           // fg class -> column cls+1
  const int t = threadIdx.x;
  const int lane = t & 63, wid = t >> 6;
  const double H = read_dim(hptr), W = read_dim(wptr);

  // ---- decode: r = t + 256u (coalesced); order irrelevant, sort fixes it ----
  ulonglong2 rk[8];
  int vmask = 0;
  #pragma unroll
  for (int u = 0; u < 8; ++u) {
    int r = t + 256 * u;
    rk[u] = make_ulonglong2(0ull, 0ull);
    if (r < R_N) {
      double p, dy, dx, eh, ew;
      if (use_ws) {
        p = prob_t[cls * R_N + r];
        const double* o = tab4 + (size_t)(cls * R_N + r) * 4;
        dy = o[0]; dx = o[1]; eh = o[2]; ew = o[3];
      } else {
        const float* sc = score + r * C1;
        double m = (double)sc[0];
        #pragma unroll
        for (int k = 1; k < C1; ++k) m = fmax(m, (double)sc[k]);
        double s = 0.0;
        #pragma unroll
        for (int k = 0; k < C1; ++k) s += exp((double)sc[k] - m);
        const float* l4 = loc + r * 84 + (cls + 1) * 4;
        p = exp((double)sc[cls + 1] - m) / s;
        dy = (double)l4[0]; dx = (double)l4[1];
        eh = exp((double)l4[2]); ew = exp((double)l4[3]);
      }
      double b0 = (double)rois[r*4+0], b1 = (double)rois[r*4+1];
      double b2 = (double)rois[r*4+2], b3 = (double)rois[r*4+3];
      double sh  = b2 - b0,       sw  = b3 - b1;
      double scy = b0 + 0.5*sh,   scx = b1 + 0.5*sw;
      double cy = dy*sh + scy,    cx = dx*sw + scx;
      double hh = eh*sh,          ww = ew*sw;
      double y1 = fmin(fmax(cy - 0.5*hh, 0.0), H);
      double x1 = fmin(fmax(cx - 0.5*ww, 0.0), W);
      double y2 = fmin(fmax(cy + 0.5*hh, 0.0), H);
      double x2 = fmin(fmax(cx + 0.5*ww, 0.0), W);
      sbd[r][0]=y1; sbd[r][1]=x1; sbd[r][2]=y2; sbd[r][3]=x2;
      bool val = p > 0.05;
      if (val) {
        rk[u] = make_ulonglong2((unsigned long long)__double_as_longlong(p),
                                (unsigned long long)(unsigned int)(~r));
        vmask |= 1 << u;
      }
    }
  }

  // ---- compaction of valid entries (block scan; order irrelevant pre-sort) ----
  int cnt = __popc(vmask);
  int x = cnt;
  #pragma unroll
  for (int off = 1; off < 64; off <<= 1) {
    int y = __shfl_up(x, off);
    if (lane >= off) x += y;
  }
  if (lane == 63) wsum[wid] = x;
  __syncthreads();
  int woff = 0;
  #pragma unroll
  for (int w2 = 0; w2 < 4; ++w2) { int s = wsum[w2]; if (w2 < wid) woff += s; }
  const int V = wsum[0] + wsum[1] + wsum[2] + wsum[3];
  int pos = woff + x - cnt;
  #pragma unroll
  for (int u = 0; u < 8; ++u)
    if ((vmask >> u) & 1) keys[pos++] = rk[u];

  int NSORT = 64; while (NSORT < V) NSORT <<= 1;
  for (int j = V + t; j < NSORT; j += 256)
    keys[j] = make_ulonglong2(0ull, (unsigned long long)(unsigned int)(~(unsigned)j));
  __syncthreads();

  // ---- bitonic sort NSORT keys, descending (prob desc, idx asc) ----
  for (int k = 2; k <= NSORT; k <<= 1) {
    for (int js = k >> 1; js > 0; js >>= 1) {
      for (int p = t; p < (NSORT >> 1); p += 256) {
        int i = ((p & ~(js - 1)) << 1) | (p & (js - 1));
        int j = i | js;
        ulonglong2 a = keys[i], b = keys[j];
        bool altb = (a.x < b.x) || (a.x == b.x && a.y < b.y);
        if (altb == ((i & k) == 0)) { keys[i] = b; keys[j] = a; }
      }
      __syncthreads();
    }
  }

  // ---- per-thread slot registers (slot j = t + 256q), f32 + idx for f64 fallback ----
  int   idx8[8];
  float fx0[8], fx1[8], fx2[8], fx3[8], far5[8];
  unsigned am = 0;
  #pragma unroll
  for (int q = 0; q < 8; ++q) {
    if (256 * q >= V) break;
    int j = t + 256 * q;
    if (j < V) {
      int idx = (int)(~(unsigned)keys[j].y);
      idx8[q] = idx;
      double a0=sbd[idx][0], a1=sbd[idx][1], a2=sbd[idx][2], a3=sbd[idx][3];
      fx0[q]=(float)a0; fx1[q]=(float)a1; fx2[q]=(float)a2; fx3[q]=(float)a3;
      far5[q]=(float)((a2-a0)*(a3-a1));
      am |= 1u << q;
    }
  }

  // ---- chunked greedy NMS ----
  const int nch = (V + 63) >> 6;
  for (int ch = 0; ch < nch; ++ch) {
    const int buf = ch & 1;
    if (wid == (ch & 3)) {
      const int q = ch >> 2;
      const int s = 64 * ch + lane;
      bool a = ((am >> q) & 1u) != 0u;
      int myidx = 0;
      double d0=0, d1=0, d2=0, d3=0, dar=0;
      if (a) {
        myidx = (int)(~(unsigned)keys[s].y);
        d0=sbd[myidx][0]; d1=sbd[myidx][1]; d2=sbd[myidx][2]; d3=sbd[myidx][3];
        dar = (d2-d0)*(d3-d1);
      }
      float f0=(float)d0, f1=(float)d1, f2=(float)d2, f3=(float)d3, fa=(float)dar;
      unsigned long long m = __ballot(a);
      unsigned long long kept = 0;
      while (m) {
        int i = __ffsll(m) - 1;
        m &= m - 1;                     // clear bit i
        kept |= 1ull << i;
        float k0=__shfl(f0,i), k1=__shfl(f1,i), k2=__shfl(f2,i), k3=__shfl(f3,i), ka=__shfl(fa,i);
        bool aliveL = ((m >> lane) & 1ull) != 0ull;   // implies lane > i
        float ty=fmaxf(k0,f0), tx=fmaxf(k1,f1);
        float by=fminf(k2,f2), bz=fminf(k3,f3);
        float w0=fmaxf(by-ty,0.f), w1=fmaxf(bz-tx,0.f);
        float inter=w0*w1;
        float uni=fmaxf(ka+fa-inter, 1e-9f);
        float rhs=0.3f*uni;
        bool kill = aliveL && (inter > rhs + FMARGIN);
        bool amb  = aliveL && !kill && (inter > rhs - FMARGIN);
        if (__any(amb)) {
          int kidx = __shfl(myidx, i);
          double b0=sbd[kidx][0], b1=sbd[kidx][1], b2=sbd[kidx][2], b3=sbd[kidx][3];
          double bar=(b2-b0)*(b3-b1);
          if (amb) {
            double ty_=fmax(b0,d0), tx_=fmax(b1,d1);
            double by_=fmin(b2,d2), bz_=fmin(b3,d3);
            double w0_=fmax(by_-ty_,0.0), w1_=fmax(bz_-tx_,0.0);
            double in_=w0_*w1_;
            double un_=bar+dar-in_;
            if (in_/fmax(un_,1e-9) > 0.3) kill = true;
          }
        }
        m &= ~__ballot(kill);
      }
      am &= ~(1u << q);                 // chunk resolved
      if ((kept >> lane) & 1ull) {
        int kpos = (int)__popcll(kept & ((1ull << lane) - 1ull));
        klist64[buf][kpos][0]=d0; klist64[buf][kpos][1]=d1;
        klist64[buf][kpos][2]=d2; klist64[buf][kpos][3]=d3; klist64[buf][kpos][4]=dar;
        klist32[buf][kpos][0]=f0; klist32[buf][kpos][1]=f1;
        klist32[buf][kpos][2]=f2; klist32[buf][kpos][3]=f3; klist32[buf][kpos][4]=fa;
        double pv = __longlong_as_double((long long)keys[s].x);
        int row = cls * R_N + s;
        out[row*5+0]=(float)d0; out[row*5+1]=(float)d1;
        out[row*5+2]=(float)d2; out[row*5+3]=(float)d3;
        out[row*5+4]=(float)pv;
        out[OUT_LBL  + row] = (float)(cls + 1);
        out[OUT_KEEP + row] = 1.0f;
      }
      if (lane == 0) kcnt[buf] = (int)__popcll(kept);
    }
    __syncthreads();
    // ---- cross suppression of future slots (f32 fast, f64 fallback) ----
    const int nk = kcnt[buf];
    const int jmin = 64 * (ch + 1);
    for (int n = 0; n < nk; ++n) {
      float k0=klist32[buf][n][0], k1=klist32[buf][n][1];
      float k2=klist32[buf][n][2], k3=klist32[buf][n][3], ka=klist32[buf][n][4];
      #pragma unroll
      for (int q2 = 0; q2 < 8; ++q2) {
        if (256 * q2 >= V) break;       // uniform: qmax cap
        int j2 = t + 256 * q2;
        if (((am >> q2) & 1u) && j2 >= jmin) {
          float ty=fmaxf(k0,fx0[q2]), tx=fmaxf(k1,fx1[q2]);
          float by=fminf(k2,fx2[q2]), bz=fminf(k3,fx3[q2]);
          float w0=fmaxf(by-ty,0.f), w1=fmaxf(bz-tx,0.f);
          float inter=w0*w1;
          float uni=fmaxf(ka+far5[q2]-inter, 1e-9f);
          float rhs=0.3f*uni;
          if (inter > rhs + FMARGIN) {
            am &= ~(1u << q2);
          } else if (inter > rhs - FMARGIN) {   // ambiguous: exact f64
            int idx = idx8[q2];
            double a0=sbd[idx][0], a1=sbd[idx][1], a2=sbd[idx][2], a3=sbd[idx][3];
            double ar_=(a2-a0)*(a3-a1);
            double b0=klist64[buf][n][0], b1=klist64[buf][n][1];
            double b2=klist64[buf][n][2], b3=klist64[buf][n][3], br=klist64[buf][n][4];
            double ty_=fmax(b0,a0), tx_=fmax(b1,a1);
            double by_=fmin(b2,a2), bz_=fmin(b3,a3);
            double w0_=fmax(by_-ty_,0.0), w1_=fmax(bz_-tx_,0.0);
            double in_=w0_*w1_;
            double un_=br+ar_-in_;
            if (in_/fmax(un_,1e-9) > 0.3) am &= ~(1u << q2);
          }
        }
      }
    }
  }
}

extern "C" void kernel_launch(void* const* d_in, const int* in_sizes, int n_in,
                              void* d_out, int out_size, void* d_ws, size_t ws_size,
                              hipStream_t stream) {
  const float* rois  = (const float*)d_in[0];
  const float* loc   = (const float*)d_in[1];
  const float* score = (const float*)d_in[2];
  const void*  hp    = d_in[3];
  const void*  wp    = d_in[4];
  float* out = (float*)d_out;

  const size_t need = (size_t)(NCLS * R_N * 4 + NCLS * R_N) * sizeof(double); // 1.6 MB
  double* tab4   = (double*)d_ws;
  double* prob_t = tab4 + (size_t)NCLS * R_N * 4;
  int use_ws = (ws_size >= need) ? 1 : 0;

  hipMemsetAsync(d_out, 0, (size_t)out_size * sizeof(float), stream);
  if (use_ws) {
    prep_kernel<<<dim3((R_N + 255)/256), dim3(256), 0, stream>>>(score, loc, tab4, prob_t);
  }
  det_kernel<<<dim3(NCLS), dim3(256), 0, stream>>>(rois, loc, score, hp, wp, out,
                                                   tab4, prob_t, use_ws);
}